// Round 3
// baseline (808.116 us; speedup 1.0000x reference)
//
#include <hip/hip_runtime.h>
#include <cstdint>
#include <cstddef>

// GCN_EW: 2-layer GCN with exp edge weights, gcn_norm w/ self-loops,
// training-mode BN, final 64->1 projection.
// B=2, N=50000, E=800000, IN=128, HID=64.
//
// R3: register-tiled GEMM (128-row tile, 8x4 micro-tile/thread, W staged
// once in LDS, K-chunked x staging with register prefetch). Old GEMM was
// L1-BW bound on per-FMA W reloads (120 us); FMA floor is ~10 us.
// Row order everywhere downstream is r = node*2 + b (batch-fused gather).

#define CAP  64
#define OCAP 65536
#define BN_EPS 1e-5f

__global__ void k_deg(const float* __restrict__ ew, const int* __restrict__ ei,
                      float* __restrict__ deg, int E) {
  int e = blockIdx.x * blockDim.x + threadIdx.x;
  if (e < E) atomicAdd(&deg[ei[(size_t)E + e]], expf(ew[e]));
}

__global__ void k_dinv(float* __restrict__ deg, int N) {
  int i = blockIdx.x * blockDim.x + threadIdx.x;
  if (i < N) deg[i] = rsqrtf(deg[i] + 1.0f);  // self-loop weight 1 included
}

// pairs[c*CAP+pos] = (src_row, bits(norm)); overflow -> exact fallback list
__global__ void k_fill(const float* __restrict__ ew, const int* __restrict__ ei,
                       const float* __restrict__ dinv, int* __restrict__ cnt,
                       int2* __restrict__ pairs,
                       int* __restrict__ ofl_cnt, int* __restrict__ ofl_list, int E) {
  int e = blockIdx.x * blockDim.x + threadIdx.x;
  if (e >= E) return;
  int r = ei[e];
  int c = ei[(size_t)E + e];
  float nrm = dinv[r] * expf(ew[e]) * dinv[c];
  int pos = atomicAdd(&cnt[c], 1);
  if (pos < CAP) {
    pairs[(size_t)c * CAP + pos] = make_int2(r, __float_as_int(nrm));
  } else {
    int o = atomicAdd(ofl_cnt, 1);
    if (o < OCAP) ofl_list[o] = e;
  }
}

// out[orow,64] = transform(in)[gr,CIN] @ W[CIN,64]
// Register-tiled: 128 rows/block, thread (rg,cg) computes rows rg+16i
// (i=0..7) x cols cg*4..+3. W staged once in LDS; x staged in 32-k chunks
// with register prefetch. TR: v -> relu(v+bias)*sc+sh applied at LDS write.
// PERM: input rows [b][node] order, output row = node*2+b.
template<int CIN, bool TR, bool PERM>
__launch_bounds__(256, 3)
__global__ void k_gemm(const float* __restrict__ in, const float* __restrict__ W,
                       float* __restrict__ out, int nrows, int N,
                       const float* __restrict__ bias, const float* __restrict__ scsh) {
  constexpr int KC = 32;           // k-chunk width
  constexpr int NC = CIN / KC;     // number of chunks
  constexpr int RT = 128;          // rows per block
  constexpr int XPAD = 36;         // xs row stride (floats): 16B-aligned,
                                   // rg-adjacent rows land on distinct banks
  __shared__ float ws[CIN * 64];   // 32 KB (CIN=128) / 16 KB
  __shared__ float xs[RT * XPAD];  // 18 KB
  __shared__ float tr[192];        // bias | scale | shift (TR only)

  int tid = threadIdx.x;
  int row0 = blockIdx.x * RT;

  // stage W (once)
  for (int s = tid; s < CIN * 16; s += 256)
    ((float4*)ws)[s] = ((const float4*)W)[s];
  if (TR) {
    for (int s = tid; s < 64; s += 256) {
      tr[s] = bias[s]; tr[64 + s] = scsh[s]; tr[128 + s] = scsh[64 + s];
    }
  }

  int rg = tid >> 4;   // 0..15
  int cg = tid & 15;   // 0..15
  int c0 = cg * 4;

  float acc[8][4];
#pragma unroll
  for (int i = 0; i < 8; ++i)
#pragma unroll
    for (int j = 0; j < 4; ++j) acc[i][j] = 0.0f;

  // staging slots: s = tid + q*256 ; r = s>>3, k = (s&7)*4
  int sr[4], sk[4];
#pragma unroll
  for (int q = 0; q < 4; ++q) {
    int s = tid + q * 256;
    sr[q] = s >> 3;
    sk[q] = (s & 7) * 4;
  }
  float4 stg[4];

  auto load_chunk = [&](int c) {
#pragma unroll
    for (int q = 0; q < 4; ++q) {
      int gr = row0 + sr[q];
      float4 v = make_float4(0.f, 0.f, 0.f, 0.f);
      if (gr < nrows)
        v = *(const float4*)(in + (size_t)gr * CIN + c * KC + sk[q]);
      stg[q] = v;
    }
  };
  auto write_chunk = [&](int c) {
#pragma unroll
    for (int q = 0; q < 4; ++q) {
      float4 v = stg[q];
      if (TR) {
        int k = c * KC + sk[q];
        v.x = fmaxf(v.x + tr[k + 0], 0.f) * tr[64 + k + 0] + tr[128 + k + 0];
        v.y = fmaxf(v.y + tr[k + 1], 0.f) * tr[64 + k + 1] + tr[128 + k + 1];
        v.z = fmaxf(v.z + tr[k + 2], 0.f) * tr[64 + k + 2] + tr[128 + k + 2];
        v.w = fmaxf(v.w + tr[k + 3], 0.f) * tr[64 + k + 3] + tr[128 + k + 3];
      }
      *(float4*)&xs[sr[q] * XPAD + sk[q]] = v;
    }
  };

  load_chunk(0);
  __syncthreads();      // ws + tr visible
  write_chunk(0);
  __syncthreads();

  for (int c = 0; c < NC; ++c) {
    if (c + 1 < NC) load_chunk(c + 1);
    int kbase = c * KC;
#pragma unroll
    for (int kk = 0; kk < KC; kk += 4) {
      float4 wv[4];
#pragma unroll
      for (int j = 0; j < 4; ++j)
        wv[j] = *(const float4*)&ws[(kbase + kk + j) * 64 + c0];
      float4 xv[8];
#pragma unroll
      for (int i = 0; i < 8; ++i)
        xv[i] = *(const float4*)&xs[(rg + i * 16) * XPAD + kk];
#pragma unroll
      for (int i = 0; i < 8; ++i) {
        float xk[4] = {xv[i].x, xv[i].y, xv[i].z, xv[i].w};
#pragma unroll
        for (int j = 0; j < 4; ++j) {
          acc[i][0] = fmaf(xk[j], wv[j].x, acc[i][0]);
          acc[i][1] = fmaf(xk[j], wv[j].y, acc[i][1]);
          acc[i][2] = fmaf(xk[j], wv[j].z, acc[i][2]);
          acc[i][3] = fmaf(xk[j], wv[j].w, acc[i][3]);
        }
      }
    }
    if (c + 1 < NC) {
      __syncthreads();
      write_chunk(c + 1);
      __syncthreads();
    }
  }

#pragma unroll
  for (int i = 0; i < 8; ++i) {
    int gr = row0 + rg + i * 16;
    if (gr < nrows) {
      int orow = PERM ? ((gr < N) ? gr * 2 : (gr - N) * 2 + 1) : gr;
      *(float4*)(out + (size_t)orow * 64 + c0) =
          make_float4(acc[i][0], acc[i][1], acc[i][2], acc[i][3]);
    }
  }
}

// One wave per node; lane i holds float2 = channels (2i,2i+1) of the 128
// batch-fused channels. raw[node][:] = self*dinv^2 + sum_k norm_k*h[row_k][:]
__global__ void k_agg(const float* __restrict__ h, const int2* __restrict__ pairs,
                      const int* __restrict__ cnt, const float* __restrict__ dinv,
                      float* __restrict__ raw, int N) {
  int node = blockIdx.x * 4 + (threadIdx.x >> 6);
  if (node >= N) return;
  int lane = threadIdx.x & 63;
  const float2* hv = (const float2*)h;      // 64 float2 per node-row
  float d = dinv[node];
  d = d * d;
  float2 self = hv[(size_t)node * 64 + lane];
  float2 acc = make_float2(self.x * d, self.y * d);
  int n = cnt[node];
  n = n > CAP ? CAP : n;
  const int2* pp = pairs + (size_t)node * CAP;
  int k = 0;
  for (; k + 4 <= n; k += 4) {
    int2 p0 = pp[k], p1 = pp[k + 1], p2 = pp[k + 2], p3 = pp[k + 3];
    float2 v0 = hv[(size_t)p0.x * 64 + lane];
    float2 v1 = hv[(size_t)p1.x * 64 + lane];
    float2 v2 = hv[(size_t)p2.x * 64 + lane];
    float2 v3 = hv[(size_t)p3.x * 64 + lane];
    float w0 = __int_as_float(p0.y), w1 = __int_as_float(p1.y);
    float w2 = __int_as_float(p2.y), w3 = __int_as_float(p3.y);
    acc.x = fmaf(w0, v0.x, acc.x); acc.y = fmaf(w0, v0.y, acc.y);
    acc.x = fmaf(w1, v1.x, acc.x); acc.y = fmaf(w1, v1.y, acc.y);
    acc.x = fmaf(w2, v2.x, acc.x); acc.y = fmaf(w2, v2.y, acc.y);
    acc.x = fmaf(w3, v3.x, acc.x); acc.y = fmaf(w3, v3.y, acc.y);
  }
  for (; k < n; ++k) {
    int2 p = pp[k];
    float2 v = hv[(size_t)p.x * 64 + lane];
    float w = __int_as_float(p.y);
    acc.x = fmaf(w, v.x, acc.x); acc.y = fmaf(w, v.y, acc.y);
  }
  ((float2*)raw)[(size_t)node * 64 + lane] = acc;
}

// Exact fallback for bucket overflow (expected empty). Layout [node][b][64].
__global__ void k_ofl(const float* __restrict__ ew, const int* __restrict__ ei,
                      const float* __restrict__ dinv, const int* __restrict__ ofl_cnt,
                      const int* __restrict__ ofl_list,
                      const float* __restrict__ h, float* __restrict__ raw,
                      int N, int E) {
  int tot = *ofl_cnt;
  if (tot > OCAP) tot = OCAP;
  for (int i = blockIdx.x * blockDim.x + threadIdx.x; i < tot;
       i += gridDim.x * blockDim.x) {
    int e = ofl_list[i];
    int r = ei[e];
    int c = ei[(size_t)E + e];
    float nrm = dinv[r] * expf(ew[e]) * dinv[c];
    for (int j = 0; j < 128; ++j)
      atomicAdd(&raw[(size_t)c * 128 + j], nrm * h[(size_t)r * 128 + j]);
  }
}

// BN sums over y = relu(raw + bias): stats[c] += sum y, stats[64+c] += sum y^2
__global__ void k_stats(const float* __restrict__ raw, const float* __restrict__ bias,
                        float* __restrict__ stats, int rows) {
  __shared__ float S[256], Q[256];
  int tid = threadIdx.x;
  int c = tid & 63, rg = tid >> 6;
  float s = 0.0f, q = 0.0f;
  for (int r = blockIdx.x * 4 + rg; r < rows; r += gridDim.x * 4) {
    float y = fmaxf(raw[(size_t)r * 64 + c] + bias[c], 0.0f);
    s += y;
    q += y * y;
  }
  S[tid] = s; Q[tid] = q;
  __syncthreads();
  if (tid < 64) {
    float ts = S[tid] + S[tid + 64] + S[tid + 128] + S[tid + 192];
    float tq = Q[tid] + Q[tid + 64] + Q[tid + 128] + Q[tid + 192];
    atomicAdd(&stats[tid], ts);
    atomicAdd(&stats[64 + tid], tq);
  }
}

__global__ void k_scale(const float* __restrict__ stats, const float* __restrict__ g,
                        const float* __restrict__ be, float* __restrict__ scsh,
                        float invCnt) {
  int c = threadIdx.x;
  if (c >= 64) return;
  float m = stats[c] * invCnt;
  float v = stats[64 + c] * invCnt - m * m;
  v = v < 0.0f ? 0.0f : v;
  float inv = rsqrtf(v + BN_EPS);
  float sc = g[c] * inv;
  scsh[c] = sc;
  scsh[64 + c] = be[c] - m * sc;
}

// rows are (node,b): r -> out[b*N + node]
__global__ void k_out(const float* __restrict__ raw, const float* __restrict__ bias,
                      const float* __restrict__ scsh, const float* __restrict__ Wc,
                      const float* __restrict__ bc, float* __restrict__ out,
                      int rows, int N) {
  int row = blockIdx.x * 4 + (threadIdx.x >> 6);
  int c = threadIdx.x & 63;
  if (row >= rows) return;
  float v = fmaxf(raw[(size_t)row * 64 + c] + bias[c], 0.0f) * scsh[c] + scsh[64 + c];
  float p = v * Wc[c];
#pragma unroll
  for (int off = 32; off > 0; off >>= 1) p += __shfl_xor(p, off, 64);
  if (c == 0) {
    int node = row >> 1, b = row & 1;
    out[(size_t)b * N + node] = p + bc[0];
  }
}

extern "C" void kernel_launch(void* const* d_in, const int* in_sizes, int n_in,
                              void* d_out, int out_size, void* d_ws, size_t ws_size,
                              hipStream_t stream) {
  const float* x   = (const float*)d_in[0];
  const float* ew  = (const float*)d_in[1];
  const float* W1  = (const float*)d_in[2];
  const float* b1  = (const float*)d_in[3];
  const float* W2  = (const float*)d_in[4];
  const float* b2  = (const float*)d_in[5];
  const float* g1  = (const float*)d_in[6];
  const float* be1 = (const float*)d_in[7];
  const float* g2  = (const float*)d_in[8];
  const float* be2 = (const float*)d_in[9];
  const float* Wc  = (const float*)d_in[10];
  const float* bc  = (const float*)d_in[11];
  const int*   ei  = (const int*)d_in[12];

  const int E  = in_sizes[1];
  const int BN = in_sizes[0] / 128;  // B*N = 100000
  const int N  = BN / 2;

  char* w = (char*)d_ws;
  size_t off = 0;
  float* dinv   = (float*)(w + off); off += (size_t)N * 4;
  int*   cnt    = (int*)  (w + off); off += (size_t)N * 4;
  float* stats1 = (float*)(w + off); off += 512;
  float* stats2 = (float*)(w + off); off += 512;
  int*   oflc   = (int*)  (w + off); off += 16;
  size_t zbytes = off;               // everything above must start at 0
  float* scsh1  = (float*)(w + off); off += 512;
  float* scsh2  = (float*)(w + off); off += 512;
  int*   ofll   = (int*)  (w + off); off += (size_t)OCAP * 4;
  off = (off + 255) & ~(size_t)255;
  int2*  pairs  = (int2*) (w + off); off += (size_t)N * CAP * 8;
  float* bufA   = (float*)(w + off); off += (size_t)BN * 64 * 4;
  float* bufB   = (float*)(w + off); off += (size_t)BN * 64 * 4;

  float* out = (float*)d_out;

  hipMemsetAsync(w, 0, zbytes, stream);

  dim3 blk(256);
  int gE  = (E + 255) / 256;
  int gN  = (N + 255) / 256;
  int gG  = (BN + 127) / 128;   // register-tiled gemm: 128 rows/block
  int gR  = (BN + 3) / 4;
  int gA  = (N + 3) / 4;        // 1 wave per node (both batches fused)

  k_deg<<<gE, blk, 0, stream>>>(ew, ei, dinv, E);
  k_dinv<<<gN, blk, 0, stream>>>(dinv, N);
  k_fill<<<gE, blk, 0, stream>>>(ew, ei, dinv, cnt, pairs, oflc, ofll, E);

  // ---- layer 1 ----  bufA = x @ W1  (rows -> node*2+b order)
  k_gemm<128, false, true><<<gG, blk, 0, stream>>>(x, W1, bufA, BN, N, nullptr, nullptr);
  k_agg<<<gA, blk, 0, stream>>>(bufA, pairs, cnt, dinv, bufB, N);
  k_ofl<<<16, blk, 0, stream>>>(ew, ei, dinv, oflc, ofll, bufA, bufB, N, E);
  k_stats<<<400, blk, 0, stream>>>(bufB, b1, stats1, BN);
  k_scale<<<1, 64, 0, stream>>>(stats1, g1, be1, scsh1, 1.0f / (float)BN);

  // ---- layer 2 ----  bufA = bn1(relu(bufB+b1)) @ W2  (row order preserved)
  k_gemm<64, true, false><<<gG, blk, 0, stream>>>(bufB, W2, bufA, BN, N, b1, scsh1);
  k_agg<<<gA, blk, 0, stream>>>(bufA, pairs, cnt, dinv, bufB, N);
  k_ofl<<<16, blk, 0, stream>>>(ew, ei, dinv, oflc, ofll, bufA, bufB, N, E);
  k_stats<<<400, blk, 0, stream>>>(bufB, b2, stats2, BN);
  k_scale<<<1, 64, 0, stream>>>(stats2, g2, be2, scsh2, 1.0f / (float)BN);

  // ---- head ----
  k_out<<<gR, blk, 0, stream>>>(bufB, b2, scsh2, Wc, bc, out, BN, N);
}

// Round 4
// 440.538 us; speedup vs baseline: 1.8344x; 1.8344x over previous
//
#include <hip/hip_runtime.h>
#include <cstdint>
#include <cstddef>

// GCN_EW: 2-layer GCN with exp edge weights, gcn_norm w/ self-loops,
// training-mode BN, final 64->1 projection.
// B=2, N=50000, E=800000, IN=128, HID=64.
//
// R4: flat register-tiled GEMM. R3's pipelined version spilled to scratch
// (934 MB WRITE_SIZE, VALUBusy 3%). This one: 64-row tile, single staging
// pass + one sync, 4x4 micro-tile/thread, W + padded x-tile in LDS,
// no lambdas, no launch_bounds. Per 4-k step: 8 ds_read_b128 vs 64 FMA.
// Row order downstream is r = node*2 + b (batch-fused gather).

#define CAP  64
#define OCAP 65536
#define BN_EPS 1e-5f

__global__ void k_deg(const float* __restrict__ ew, const int* __restrict__ ei,
                      float* __restrict__ deg, int E) {
  int e = blockIdx.x * blockDim.x + threadIdx.x;
  if (e < E) atomicAdd(&deg[ei[(size_t)E + e]], expf(ew[e]));
}

__global__ void k_dinv(float* __restrict__ deg, int N) {
  int i = blockIdx.x * blockDim.x + threadIdx.x;
  if (i < N) deg[i] = rsqrtf(deg[i] + 1.0f);  // self-loop weight 1 included
}

// pairs[c*CAP+pos] = (src_row, bits(norm)); overflow -> exact fallback list
__global__ void k_fill(const float* __restrict__ ew, const int* __restrict__ ei,
                       const float* __restrict__ dinv, int* __restrict__ cnt,
                       int2* __restrict__ pairs,
                       int* __restrict__ ofl_cnt, int* __restrict__ ofl_list, int E) {
  int e = blockIdx.x * blockDim.x + threadIdx.x;
  if (e >= E) return;
  int r = ei[e];
  int c = ei[(size_t)E + e];
  float nrm = dinv[r] * expf(ew[e]) * dinv[c];
  int pos = atomicAdd(&cnt[c], 1);
  if (pos < CAP) {
    pairs[(size_t)c * CAP + pos] = make_int2(r, __float_as_int(nrm));
  } else {
    int o = atomicAdd(ofl_cnt, 1);
    if (o < OCAP) ofl_list[o] = e;
  }
}

// out[orow,64] = transform(in)[gr,CIN] @ W[CIN,64]
// 64 rows/block; thread (rg=tid>>4, cg=tid&15) computes rows rg*4..+3,
// cols cg*4..+3. W staged once in LDS [k][64]; x-tile staged with row
// stride CIN+4 (2-way banks only). TR: relu(v+bias)*sc+sh at staging,
// reading bias/scsh straight from global (L1-hot).
// PERM: input rows [b][node] order, output row = node*2+b.
template<int CIN, bool TR, bool PERM>
__global__ void k_gemm(const float* __restrict__ in, const float* __restrict__ W,
                       float* __restrict__ out, int nrows, int N,
                       const float* __restrict__ bias, const float* __restrict__ scsh) {
  constexpr int RT = 64;           // rows per block
  constexpr int XS = CIN + 4;      // xs row stride (floats), 16B-aligned
  constexpr int KV = CIN / 4;      // float4 per row
  __shared__ float ws[CIN * 64];   // 32 KB (CIN=128) / 16 KB
  __shared__ float xs[RT * XS];    // 33 KB / 17 KB

  int tid = threadIdx.x;
  int row0 = blockIdx.x * RT;

  // stage W (once): CIN*16 float4
  for (int s = tid; s < CIN * 16; s += 256)
    ((float4*)ws)[s] = ((const float4*)W)[s];

  // stage x tile: RT*KV float4 slots
  for (int s = tid; s < RT * KV; s += 256) {
    int r = s / KV, k4 = s - r * KV;
    int gr = row0 + r;
    float4 v = make_float4(0.f, 0.f, 0.f, 0.f);
    if (gr < nrows)
      v = *(const float4*)(in + (size_t)gr * CIN + k4 * 4);
    if (TR) {
      float4 bb = *(const float4*)(bias + k4 * 4);
      float4 sc = *(const float4*)(scsh + k4 * 4);
      float4 sh = *(const float4*)(scsh + 64 + k4 * 4);
      v.x = fmaxf(v.x + bb.x, 0.f) * sc.x + sh.x;
      v.y = fmaxf(v.y + bb.y, 0.f) * sc.y + sh.y;
      v.z = fmaxf(v.z + bb.z, 0.f) * sc.z + sh.z;
      v.w = fmaxf(v.w + bb.w, 0.f) * sc.w + sh.w;
    }
    *(float4*)&xs[r * XS + k4 * 4] = v;
  }
  __syncthreads();

  int rg = tid >> 4;    // 0..15
  int cg = tid & 15;    // 0..15
  int c0 = cg * 4;
  int r0 = rg * 4;

  float acc[4][4];
#pragma unroll
  for (int i = 0; i < 4; ++i)
#pragma unroll
    for (int j = 0; j < 4; ++j) acc[i][j] = 0.0f;

#pragma unroll 2
  for (int k = 0; k < CIN; k += 4) {
    float4 wv0 = *(const float4*)&ws[(k + 0) * 64 + c0];
    float4 wv1 = *(const float4*)&ws[(k + 1) * 64 + c0];
    float4 wv2 = *(const float4*)&ws[(k + 2) * 64 + c0];
    float4 wv3 = *(const float4*)&ws[(k + 3) * 64 + c0];
#pragma unroll
    for (int i = 0; i < 4; ++i) {
      float4 xv = *(const float4*)&xs[(r0 + i) * XS + k];
      acc[i][0] = fmaf(xv.x, wv0.x, acc[i][0]);
      acc[i][1] = fmaf(xv.x, wv0.y, acc[i][1]);
      acc[i][2] = fmaf(xv.x, wv0.z, acc[i][2]);
      acc[i][3] = fmaf(xv.x, wv0.w, acc[i][3]);
      acc[i][0] = fmaf(xv.y, wv1.x, acc[i][0]);
      acc[i][1] = fmaf(xv.y, wv1.y, acc[i][1]);
      acc[i][2] = fmaf(xv.y, wv1.z, acc[i][2]);
      acc[i][3] = fmaf(xv.y, wv1.w, acc[i][3]);
      acc[i][0] = fmaf(xv.z, wv2.x, acc[i][0]);
      acc[i][1] = fmaf(xv.z, wv2.y, acc[i][1]);
      acc[i][2] = fmaf(xv.z, wv2.z, acc[i][2]);
      acc[i][3] = fmaf(xv.z, wv2.w, acc[i][3]);
      acc[i][0] = fmaf(xv.w, wv3.x, acc[i][0]);
      acc[i][1] = fmaf(xv.w, wv3.y, acc[i][1]);
      acc[i][2] = fmaf(xv.w, wv3.z, acc[i][2]);
      acc[i][3] = fmaf(xv.w, wv3.w, acc[i][3]);
    }
  }

#pragma unroll
  for (int i = 0; i < 4; ++i) {
    int gr = row0 + r0 + i;
    if (gr < nrows) {
      int orow = PERM ? ((gr < N) ? gr * 2 : (gr - N) * 2 + 1) : gr;
      *(float4*)(out + (size_t)orow * 64 + c0) =
          make_float4(acc[i][0], acc[i][1], acc[i][2], acc[i][3]);
    }
  }
}

// One wave per node; lane i holds float2 = channels (2i,2i+1) of the 128
// batch-fused channels. raw[node][:] = self*dinv^2 + sum_k norm_k*h[row_k][:]
__global__ void k_agg(const float* __restrict__ h, const int2* __restrict__ pairs,
                      const int* __restrict__ cnt, const float* __restrict__ dinv,
                      float* __restrict__ raw, int N) {
  int node = blockIdx.x * 4 + (threadIdx.x >> 6);
  if (node >= N) return;
  int lane = threadIdx.x & 63;
  const float2* hv = (const float2*)h;      // 64 float2 per node-row
  float d = dinv[node];
  d = d * d;
  float2 self = hv[(size_t)node * 64 + lane];
  float2 acc = make_float2(self.x * d, self.y * d);
  int n = cnt[node];
  n = n > CAP ? CAP : n;
  const int2* pp = pairs + (size_t)node * CAP;
  int k = 0;
  for (; k + 4 <= n; k += 4) {
    int2 p0 = pp[k], p1 = pp[k + 1], p2 = pp[k + 2], p3 = pp[k + 3];
    float2 v0 = hv[(size_t)p0.x * 64 + lane];
    float2 v1 = hv[(size_t)p1.x * 64 + lane];
    float2 v2 = hv[(size_t)p2.x * 64 + lane];
    float2 v3 = hv[(size_t)p3.x * 64 + lane];
    float w0 = __int_as_float(p0.y), w1 = __int_as_float(p1.y);
    float w2 = __int_as_float(p2.y), w3 = __int_as_float(p3.y);
    acc.x = fmaf(w0, v0.x, acc.x); acc.y = fmaf(w0, v0.y, acc.y);
    acc.x = fmaf(w1, v1.x, acc.x); acc.y = fmaf(w1, v1.y, acc.y);
    acc.x = fmaf(w2, v2.x, acc.x); acc.y = fmaf(w2, v2.y, acc.y);
    acc.x = fmaf(w3, v3.x, acc.x); acc.y = fmaf(w3, v3.y, acc.y);
  }
  for (; k < n; ++k) {
    int2 p = pp[k];
    float2 v = hv[(size_t)p.x * 64 + lane];
    float w = __int_as_float(p.y);
    acc.x = fmaf(w, v.x, acc.x); acc.y = fmaf(w, v.y, acc.y);
  }
  ((float2*)raw)[(size_t)node * 64 + lane] = acc;
}

// Exact fallback for bucket overflow (expected empty). Layout [node][b][64].
__global__ void k_ofl(const float* __restrict__ ew, const int* __restrict__ ei,
                      const float* __restrict__ dinv, const int* __restrict__ ofl_cnt,
                      const int* __restrict__ ofl_list,
                      const float* __restrict__ h, float* __restrict__ raw,
                      int N, int E) {
  int tot = *ofl_cnt;
  if (tot > OCAP) tot = OCAP;
  for (int i = blockIdx.x * blockDim.x + threadIdx.x; i < tot;
       i += gridDim.x * blockDim.x) {
    int e = ofl_list[i];
    int r = ei[e];
    int c = ei[(size_t)E + e];
    float nrm = dinv[r] * expf(ew[e]) * dinv[c];
    for (int j = 0; j < 128; ++j)
      atomicAdd(&raw[(size_t)c * 128 + j], nrm * h[(size_t)r * 128 + j]);
  }
}

// BN sums over y = relu(raw + bias): stats[c] += sum y, stats[64+c] += sum y^2
__global__ void k_stats(const float* __restrict__ raw, const float* __restrict__ bias,
                        float* __restrict__ stats, int rows) {
  __shared__ float S[256], Q[256];
  int tid = threadIdx.x;
  int c = tid & 63, rg = tid >> 6;
  float s = 0.0f, q = 0.0f;
  for (int r = blockIdx.x * 4 + rg; r < rows; r += gridDim.x * 4) {
    float y = fmaxf(raw[(size_t)r * 64 + c] + bias[c], 0.0f);
    s += y;
    q += y * y;
  }
  S[tid] = s; Q[tid] = q;
  __syncthreads();
  if (tid < 64) {
    float ts = S[tid] + S[tid + 64] + S[tid + 128] + S[tid + 192];
    float tq = Q[tid] + Q[tid + 64] + Q[tid + 128] + Q[tid + 192];
    atomicAdd(&stats[tid], ts);
    atomicAdd(&stats[64 + tid], tq);
  }
}

__global__ void k_scale(const float* __restrict__ stats, const float* __restrict__ g,
                        const float* __restrict__ be, float* __restrict__ scsh,
                        float invCnt) {
  int c = threadIdx.x;
  if (c >= 64) return;
  float m = stats[c] * invCnt;
  float v = stats[64 + c] * invCnt - m * m;
  v = v < 0.0f ? 0.0f : v;
  float inv = rsqrtf(v + BN_EPS);
  float sc = g[c] * inv;
  scsh[c] = sc;
  scsh[64 + c] = be[c] - m * sc;
}

// rows are (node,b): r -> out[b*N + node]
__global__ void k_out(const float* __restrict__ raw, const float* __restrict__ bias,
                      const float* __restrict__ scsh, const float* __restrict__ Wc,
                      const float* __restrict__ bc, float* __restrict__ out,
                      int rows, int N) {
  int row = blockIdx.x * 4 + (threadIdx.x >> 6);
  int c = threadIdx.x & 63;
  if (row >= rows) return;
  float v = fmaxf(raw[(size_t)row * 64 + c] + bias[c], 0.0f) * scsh[c] + scsh[64 + c];
  float p = v * Wc[c];
#pragma unroll
  for (int off = 32; off > 0; off >>= 1) p += __shfl_xor(p, off, 64);
  if (c == 0) {
    int node = row >> 1, b = row & 1;
    out[(size_t)b * N + node] = p + bc[0];
  }
}

extern "C" void kernel_launch(void* const* d_in, const int* in_sizes, int n_in,
                              void* d_out, int out_size, void* d_ws, size_t ws_size,
                              hipStream_t stream) {
  const float* x   = (const float*)d_in[0];
  const float* ew  = (const float*)d_in[1];
  const float* W1  = (const float*)d_in[2];
  const float* b1  = (const float*)d_in[3];
  const float* W2  = (const float*)d_in[4];
  const float* b2  = (const float*)d_in[5];
  const float* g1  = (const float*)d_in[6];
  const float* be1 = (const float*)d_in[7];
  const float* g2  = (const float*)d_in[8];
  const float* be2 = (const float*)d_in[9];
  const float* Wc  = (const float*)d_in[10];
  const float* bc  = (const float*)d_in[11];
  const int*   ei  = (const int*)d_in[12];

  const int E  = in_sizes[1];
  const int BN = in_sizes[0] / 128;  // B*N = 100000
  const int N  = BN / 2;

  char* w = (char*)d_ws;
  size_t off = 0;
  float* dinv   = (float*)(w + off); off += (size_t)N * 4;
  int*   cnt    = (int*)  (w + off); off += (size_t)N * 4;
  float* stats1 = (float*)(w + off); off += 512;
  float* stats2 = (float*)(w + off); off += 512;
  int*   oflc   = (int*)  (w + off); off += 16;
  size_t zbytes = off;               // everything above must start at 0
  float* scsh1  = (float*)(w + off); off += 512;
  float* scsh2  = (float*)(w + off); off += 512;
  int*   ofll   = (int*)  (w + off); off += (size_t)OCAP * 4;
  off = (off + 255) & ~(size_t)255;
  int2*  pairs  = (int2*) (w + off); off += (size_t)N * CAP * 8;
  float* bufA   = (float*)(w + off); off += (size_t)BN * 64 * 4;
  float* bufB   = (float*)(w + off); off += (size_t)BN * 64 * 4;

  float* out = (float*)d_out;

  hipMemsetAsync(w, 0, zbytes, stream);

  dim3 blk(256);
  int gE  = (E + 255) / 256;
  int gN  = (N + 255) / 256;
  int gG  = (BN + 63) / 64;     // register-tiled gemm: 64 rows/block
  int gR  = (BN + 3) / 4;
  int gA  = (N + 3) / 4;        // 1 wave per node (both batches fused)

  k_deg<<<gE, blk, 0, stream>>>(ew, ei, dinv, E);
  k_dinv<<<gN, blk, 0, stream>>>(dinv, N);
  k_fill<<<gE, blk, 0, stream>>>(ew, ei, dinv, cnt, pairs, oflc, ofll, E);

  // ---- layer 1 ----  bufA = x @ W1  (rows -> node*2+b order)
  k_gemm<128, false, true><<<gG, blk, 0, stream>>>(x, W1, bufA, BN, N, nullptr, nullptr);
  k_agg<<<gA, blk, 0, stream>>>(bufA, pairs, cnt, dinv, bufB, N);
  k_ofl<<<16, blk, 0, stream>>>(ew, ei, dinv, oflc, ofll, bufA, bufB, N, E);
  k_stats<<<400, blk, 0, stream>>>(bufB, b1, stats1, BN);
  k_scale<<<1, 64, 0, stream>>>(stats1, g1, be1, scsh1, 1.0f / (float)BN);

  // ---- layer 2 ----  bufA = bn1(relu(bufB+b1)) @ W2  (row order preserved)
  k_gemm<64, true, false><<<gG, blk, 0, stream>>>(bufB, W2, bufA, BN, N, b1, scsh1);
  k_agg<<<gA, blk, 0, stream>>>(bufA, pairs, cnt, dinv, bufB, N);
  k_ofl<<<16, blk, 0, stream>>>(ew, ei, dinv, oflc, ofll, bufA, bufB, N, E);
  k_stats<<<400, blk, 0, stream>>>(bufB, b2, stats2, BN);
  k_scale<<<1, 64, 0, stream>>>(stats2, g2, be2, scsh2, 1.0f / (float)BN);

  // ---- head ----
  k_out<<<gR, blk, 0, stream>>>(bufB, b2, scsh2, Wc, bc, out, BN, N);
}

// Round 5
// 394.335 us; speedup vs baseline: 2.0493x; 1.1172x over previous
//
#include <hip/hip_runtime.h>
#include <hip/hip_fp16.h>
#include <cstdint>
#include <cstddef>

// GCN_EW: 2-layer GCN with exp edge weights, gcn_norm w/ self-loops,
// training-mode BN, final 64->1 projection.
// B=2, N=50000, E=800000, IN=128, HID=64.
//
// R5: fp16 intermediate buffers (h and raw agg) -> gather bytes halved
// (node row = 256 B = two 128B lines), 8-deep gather unroll for MLP.
// fp32 math everywhere; fp16 only as storage. k_ofl uses CAS on half2
// (expected zero iterations; kept for exactness).
// Row order downstream is r = node*2 + b (batch-fused gather).

#define CAP  64
#define OCAP 65536
#define BN_EPS 1e-5f

static __device__ __forceinline__ unsigned h2u(__half2 h) {
  union { __half2 h; unsigned u; } c; c.h = h; return c.u;
}
static __device__ __forceinline__ __half2 u2h(unsigned u) {
  union { unsigned u; __half2 h; } c; c.u = u; return c.h;
}

__global__ void k_deg(const float* __restrict__ ew, const int* __restrict__ ei,
                      float* __restrict__ deg, int E) {
  int e = blockIdx.x * blockDim.x + threadIdx.x;
  if (e < E) atomicAdd(&deg[ei[(size_t)E + e]], expf(ew[e]));
}

__global__ void k_dinv(float* __restrict__ deg, int N) {
  int i = blockIdx.x * blockDim.x + threadIdx.x;
  if (i < N) deg[i] = rsqrtf(deg[i] + 1.0f);  // self-loop weight 1 included
}

// pairs[c*CAP+pos] = (src_row, bits(norm)); overflow -> exact fallback list
__global__ void k_fill(const float* __restrict__ ew, const int* __restrict__ ei,
                       const float* __restrict__ dinv, int* __restrict__ cnt,
                       int2* __restrict__ pairs,
                       int* __restrict__ ofl_cnt, int* __restrict__ ofl_list, int E) {
  int e = blockIdx.x * blockDim.x + threadIdx.x;
  if (e >= E) return;
  int r = ei[e];
  int c = ei[(size_t)E + e];
  float nrm = dinv[r] * expf(ew[e]) * dinv[c];
  int pos = atomicAdd(&cnt[c], 1);
  if (pos < CAP) {
    pairs[(size_t)c * CAP + pos] = make_int2(r, __float_as_int(nrm));
  } else {
    int o = atomicAdd(ofl_cnt, 1);
    if (o < OCAP) ofl_list[o] = e;
  }
}

// out[orow,64](fp16) = transform(in)[gr,CIN] @ W[CIN,64]
// 64 rows/block; thread (rg,cg) computes rows rg*4..+3, cols cg*4..+3.
// W staged in LDS [k][64]; x-tile staged fp32 with row stride CIN+4.
// TR: input is fp16 raw; v -> relu(v+bias)*sc+sh at staging.
// PERM: input rows [b][node] order, output row = node*2+b.
template<int CIN, bool TR, bool PERM>
__global__ void k_gemm(const void* __restrict__ in_, const float* __restrict__ W,
                       __half* __restrict__ out, int nrows, int N,
                       const float* __restrict__ bias, const float* __restrict__ scsh) {
  constexpr int RT = 64;           // rows per block
  constexpr int XS = CIN + 4;      // xs row stride (floats), 16B-aligned
  constexpr int KV = CIN / 4;      // 4-channel slots per row
  __shared__ float ws[CIN * 64];
  __shared__ float xs[RT * XS];

  int tid = threadIdx.x;
  int row0 = blockIdx.x * RT;

  // stage W (once): CIN*16 float4
  for (int s = tid; s < CIN * 16; s += 256)
    ((float4*)ws)[s] = ((const float4*)W)[s];

  // stage x tile: RT*KV slots of 4 channels
  for (int s = tid; s < RT * KV; s += 256) {
    int r = s / KV, k4 = s - r * KV;
    int gr = row0 + r;
    float4 v = make_float4(0.f, 0.f, 0.f, 0.f);
    if (gr < nrows) {
      if (TR) {
        const __half* in = (const __half*)in_;
        uint2 u = *(const uint2*)(in + (size_t)gr * CIN + k4 * 4);
        float2 fa = __half22float2(u2h(u.x));
        float2 fb = __half22float2(u2h(u.y));
        v = make_float4(fa.x, fa.y, fb.x, fb.y);
      } else {
        const float* in = (const float*)in_;
        v = *(const float4*)(in + (size_t)gr * CIN + k4 * 4);
      }
    }
    if (TR) {
      float4 bb = *(const float4*)(bias + k4 * 4);
      float4 sc = *(const float4*)(scsh + k4 * 4);
      float4 sh = *(const float4*)(scsh + 64 + k4 * 4);
      v.x = fmaxf(v.x + bb.x, 0.f) * sc.x + sh.x;
      v.y = fmaxf(v.y + bb.y, 0.f) * sc.y + sh.y;
      v.z = fmaxf(v.z + bb.z, 0.f) * sc.z + sh.z;
      v.w = fmaxf(v.w + bb.w, 0.f) * sc.w + sh.w;
    }
    *(float4*)&xs[r * XS + k4 * 4] = v;
  }
  __syncthreads();

  int rg = tid >> 4;    // 0..15
  int cg = tid & 15;    // 0..15
  int c0 = cg * 4;
  int r0 = rg * 4;

  float acc[4][4];
#pragma unroll
  for (int i = 0; i < 4; ++i)
#pragma unroll
    for (int j = 0; j < 4; ++j) acc[i][j] = 0.0f;

#pragma unroll 2
  for (int k = 0; k < CIN; k += 4) {
    float4 wv0 = *(const float4*)&ws[(k + 0) * 64 + c0];
    float4 wv1 = *(const float4*)&ws[(k + 1) * 64 + c0];
    float4 wv2 = *(const float4*)&ws[(k + 2) * 64 + c0];
    float4 wv3 = *(const float4*)&ws[(k + 3) * 64 + c0];
#pragma unroll
    for (int i = 0; i < 4; ++i) {
      float4 xv = *(const float4*)&xs[(r0 + i) * XS + k];
      acc[i][0] = fmaf(xv.x, wv0.x, acc[i][0]);
      acc[i][1] = fmaf(xv.x, wv0.y, acc[i][1]);
      acc[i][2] = fmaf(xv.x, wv0.z, acc[i][2]);
      acc[i][3] = fmaf(xv.x, wv0.w, acc[i][3]);
      acc[i][0] = fmaf(xv.y, wv1.x, acc[i][0]);
      acc[i][1] = fmaf(xv.y, wv1.y, acc[i][1]);
      acc[i][2] = fmaf(xv.y, wv1.z, acc[i][2]);
      acc[i][3] = fmaf(xv.y, wv1.w, acc[i][3]);
      acc[i][0] = fmaf(xv.z, wv2.x, acc[i][0]);
      acc[i][1] = fmaf(xv.z, wv2.y, acc[i][1]);
      acc[i][2] = fmaf(xv.z, wv2.z, acc[i][2]);
      acc[i][3] = fmaf(xv.z, wv2.w, acc[i][3]);
      acc[i][0] = fmaf(xv.w, wv3.x, acc[i][0]);
      acc[i][1] = fmaf(xv.w, wv3.y, acc[i][1]);
      acc[i][2] = fmaf(xv.w, wv3.z, acc[i][2]);
      acc[i][3] = fmaf(xv.w, wv3.w, acc[i][3]);
    }
  }

#pragma unroll
  for (int i = 0; i < 4; ++i) {
    int gr = row0 + r0 + i;
    if (gr < nrows) {
      int orow = PERM ? ((gr < N) ? gr * 2 : (gr - N) * 2 + 1) : gr;
      __half2 h01 = __floats2half2_rn(acc[i][0], acc[i][1]);
      __half2 h23 = __floats2half2_rn(acc[i][2], acc[i][3]);
      *(uint2*)(out + (size_t)orow * 64 + c0) = make_uint2(h2u(h01), h2u(h23));
    }
  }
}

// One wave per node; lane i holds half2 = channels (2i,2i+1) of the 128
// batch-fused channels. raw[node][:] = self*dinv^2 + sum_k norm_k*h[row_k][:]
__global__ void k_agg(const __half* __restrict__ h, const int2* __restrict__ pairs,
                      const int* __restrict__ cnt, const float* __restrict__ dinv,
                      __half* __restrict__ raw, int N) {
  int node = blockIdx.x * 4 + (threadIdx.x >> 6);
  if (node >= N) return;
  int lane = threadIdx.x & 63;
  const __half2* hv = (const __half2*)h;    // 64 half2 per node-row (256 B)
  float d = dinv[node];
  d = d * d;
  float2 self = __half22float2(hv[(size_t)node * 64 + lane]);
  float2 acc = make_float2(self.x * d, self.y * d);
  int n = cnt[node];
  n = n > CAP ? CAP : n;
  const int2* pp = pairs + (size_t)node * CAP;
  int k = 0;
  for (; k + 8 <= n; k += 8) {
    int2 p[8];
#pragma unroll
    for (int q = 0; q < 8; ++q) p[q] = pp[k + q];
    __half2 v[8];
#pragma unroll
    for (int q = 0; q < 8; ++q) v[q] = hv[(size_t)p[q].x * 64 + lane];
#pragma unroll
    for (int q = 0; q < 8; ++q) {
      float w = __int_as_float(p[q].y);
      float2 f = __half22float2(v[q]);
      acc.x = fmaf(w, f.x, acc.x);
      acc.y = fmaf(w, f.y, acc.y);
    }
  }
  for (; k < n; ++k) {
    int2 p = pp[k];
    float2 f = __half22float2(hv[(size_t)p.x * 64 + lane]);
    float w = __int_as_float(p.y);
    acc.x = fmaf(w, f.x, acc.x);
    acc.y = fmaf(w, f.y, acc.y);
  }
  ((__half2*)raw)[(size_t)node * 64 + lane] = __floats2half2_rn(acc.x, acc.y);
}

// Exact fallback for bucket overflow (expected empty). CAS on packed half2.
__global__ void k_ofl(const float* __restrict__ ew, const int* __restrict__ ei,
                      const float* __restrict__ dinv, const int* __restrict__ ofl_cnt,
                      const int* __restrict__ ofl_list,
                      const __half* __restrict__ h, __half* __restrict__ raw,
                      int N, int E) {
  int tot = *ofl_cnt;
  if (tot > OCAP) tot = OCAP;
  for (int i = blockIdx.x * blockDim.x + threadIdx.x; i < tot;
       i += gridDim.x * blockDim.x) {
    int e = ofl_list[i];
    int r = ei[e];
    int c = ei[(size_t)E + e];
    float nrm = dinv[r] * expf(ew[e]) * dinv[c];
    const __half2* hr = (const __half2*)(h + (size_t)r * 128);
    unsigned* dst = (unsigned*)(raw + (size_t)c * 128);
    for (int j = 0; j < 64; ++j) {
      float2 hv2 = __half22float2(hr[j]);
      unsigned old = dst[j], assumed;
      do {
        assumed = old;
        float2 cur = __half22float2(u2h(assumed));
        __half2 nv = __floats2half2_rn(cur.x + nrm * hv2.x, cur.y + nrm * hv2.y);
        old = atomicCAS(&dst[j], assumed, h2u(nv));
      } while (old != assumed);
    }
  }
}

// BN sums over y = relu(raw + bias): stats[c] += sum y, stats[64+c] += sum y^2
__global__ void k_stats(const __half* __restrict__ raw, const float* __restrict__ bias,
                        float* __restrict__ stats, int rows) {
  __shared__ float S[256], Q[256];
  int tid = threadIdx.x;
  int c = tid & 63, rg = tid >> 6;
  float s = 0.0f, q = 0.0f;
  for (int r = blockIdx.x * 4 + rg; r < rows; r += gridDim.x * 4) {
    float y = fmaxf(__half2float(raw[(size_t)r * 64 + c]) + bias[c], 0.0f);
    s += y;
    q += y * y;
  }
  S[tid] = s; Q[tid] = q;
  __syncthreads();
  if (tid < 64) {
    float ts = S[tid] + S[tid + 64] + S[tid + 128] + S[tid + 192];
    float tq = Q[tid] + Q[tid + 64] + Q[tid + 128] + Q[tid + 192];
    atomicAdd(&stats[tid], ts);
    atomicAdd(&stats[64 + tid], tq);
  }
}

__global__ void k_scale(const float* __restrict__ stats, const float* __restrict__ g,
                        const float* __restrict__ be, float* __restrict__ scsh,
                        float invCnt) {
  int c = threadIdx.x;
  if (c >= 64) return;
  float m = stats[c] * invCnt;
  float v = stats[64 + c] * invCnt - m * m;
  v = v < 0.0f ? 0.0f : v;
  float inv = rsqrtf(v + BN_EPS);
  float sc = g[c] * inv;
  scsh[c] = sc;
  scsh[64 + c] = be[c] - m * sc;
}

// rows are (node,b): r -> out[b*N + node]
__global__ void k_out(const __half* __restrict__ raw, const float* __restrict__ bias,
                      const float* __restrict__ scsh, const float* __restrict__ Wc,
                      const float* __restrict__ bc, float* __restrict__ out,
                      int rows, int N) {
  int row = blockIdx.x * 4 + (threadIdx.x >> 6);
  int c = threadIdx.x & 63;
  if (row >= rows) return;
  float v = fmaxf(__half2float(raw[(size_t)row * 64 + c]) + bias[c], 0.0f)
              * scsh[c] + scsh[64 + c];
  float p = v * Wc[c];
#pragma unroll
  for (int off = 32; off > 0; off >>= 1) p += __shfl_xor(p, off, 64);
  if (c == 0) {
    int node = row >> 1, b = row & 1;
    out[(size_t)b * N + node] = p + bc[0];
  }
}

extern "C" void kernel_launch(void* const* d_in, const int* in_sizes, int n_in,
                              void* d_out, int out_size, void* d_ws, size_t ws_size,
                              hipStream_t stream) {
  const float* x   = (const float*)d_in[0];
  const float* ew  = (const float*)d_in[1];
  const float* W1  = (const float*)d_in[2];
  const float* b1  = (const float*)d_in[3];
  const float* W2  = (const float*)d_in[4];
  const float* b2  = (const float*)d_in[5];
  const float* g1  = (const float*)d_in[6];
  const float* be1 = (const float*)d_in[7];
  const float* g2  = (const float*)d_in[8];
  const float* be2 = (const float*)d_in[9];
  const float* Wc  = (const float*)d_in[10];
  const float* bc  = (const float*)d_in[11];
  const int*   ei  = (const int*)d_in[12];

  const int E  = in_sizes[1];
  const int BN = in_sizes[0] / 128;  // B*N = 100000
  const int N  = BN / 2;

  char* w = (char*)d_ws;
  size_t off = 0;
  float* dinv   = (float*)(w + off); off += (size_t)N * 4;
  int*   cnt    = (int*)  (w + off); off += (size_t)N * 4;
  float* stats1 = (float*)(w + off); off += 512;
  float* stats2 = (float*)(w + off); off += 512;
  int*   oflc   = (int*)  (w + off); off += 16;
  size_t zbytes = off;               // everything above must start at 0
  float* scsh1  = (float*)(w + off); off += 512;
  float* scsh2  = (float*)(w + off); off += 512;
  int*   ofll   = (int*)  (w + off); off += (size_t)OCAP * 4;
  off = (off + 255) & ~(size_t)255;
  int2*   pairs = (int2*)  (w + off); off += (size_t)N * CAP * 8;
  __half* bufA  = (__half*)(w + off); off += (size_t)BN * 64 * 2;
  __half* bufB  = (__half*)(w + off); off += (size_t)BN * 64 * 2;

  float* out = (float*)d_out;

  hipMemsetAsync(w, 0, zbytes, stream);

  dim3 blk(256);
  int gE  = (E + 255) / 256;
  int gN  = (N + 255) / 256;
  int gG  = (BN + 63) / 64;     // register-tiled gemm: 64 rows/block
  int gR  = (BN + 3) / 4;
  int gA  = (N + 3) / 4;        // 1 wave per node (both batches fused)

  k_deg<<<gE, blk, 0, stream>>>(ew, ei, dinv, E);
  k_dinv<<<gN, blk, 0, stream>>>(dinv, N);
  k_fill<<<gE, blk, 0, stream>>>(ew, ei, dinv, cnt, pairs, oflc, ofll, E);

  // ---- layer 1 ----  bufA = x @ W1  (rows -> node*2+b order)
  k_gemm<128, false, true><<<gG, blk, 0, stream>>>(x, W1, bufA, BN, N, nullptr, nullptr);
  k_agg<<<gA, blk, 0, stream>>>(bufA, pairs, cnt, dinv, bufB, N);
  k_ofl<<<16, blk, 0, stream>>>(ew, ei, dinv, oflc, ofll, bufA, bufB, N, E);
  k_stats<<<400, blk, 0, stream>>>(bufB, b1, stats1, BN);
  k_scale<<<1, 64, 0, stream>>>(stats1, g1, be1, scsh1, 1.0f / (float)BN);

  // ---- layer 2 ----  bufA = bn1(relu(bufB+b1)) @ W2  (row order preserved)
  k_gemm<64, true, false><<<gG, blk, 0, stream>>>(bufB, W2, bufA, BN, N, b1, scsh1);
  k_agg<<<gA, blk, 0, stream>>>(bufA, pairs, cnt, dinv, bufB, N);
  k_ofl<<<16, blk, 0, stream>>>(ew, ei, dinv, oflc, ofll, bufA, bufB, N, E);
  k_stats<<<400, blk, 0, stream>>>(bufB, b2, stats2, BN);
  k_scale<<<1, 64, 0, stream>>>(stats2, g2, be2, scsh2, 1.0f / (float)BN);

  // ---- head ----
  k_out<<<gR, blk, 0, stream>>>(bufB, b2, scsh2, Wc, bc, out, BN, N);
}

// Round 6
// 362.434 us; speedup vs baseline: 2.2297x; 1.0880x over previous
//
#include <hip/hip_runtime.h>
#include <hip/hip_fp16.h>
#include <cstdint>
#include <cstddef>

// GCN_EW: 2-layer GCN with exp edge weights, gcn_norm w/ self-loops,
// training-mode BN, final 64->1 projection.
// B=2, N=50000, E=800000, IN=128, HID=64.
//
// R6: (1) k_deg's 800K atomics replaced by bucket-scan degree (k_degb:
// wave/node coalesced read + shfl reduce); k_fill stores (src, exp(ew))
// with no dinv dependency; k_agg applies dinv[src] per edge (broadcast
// load) and dinv[c] at the end. (2) GEMM K-chunked: 16KB W-chunk +
// 17.4KB x-tile = 33.4KB LDS -> 4 blocks/CU (was 65KB -> 2). (3) k_fill
// 4-deep unrolled (atomic MLP probe).
// Row order downstream is r = node*2 + b (batch-fused gather).

#define CAP  64
#define OCAP 65536
#define BN_EPS 1e-5f

static __device__ __forceinline__ unsigned h2u(__half2 h) {
  union { __half2 h; unsigned u; } c; c.h = h; return c.u;
}
static __device__ __forceinline__ __half2 u2h(unsigned u) {
  union { unsigned u; __half2 h; } c; c.u = u; return c.h;
}

// pairs[c*CAP+pos] = (src_row, bits(exp(ew))); overflow -> fallback list
__global__ void k_fill(const float* __restrict__ ew, const int* __restrict__ ei,
                       int* __restrict__ cnt, int2* __restrict__ pairs,
                       int* __restrict__ ofl_cnt, int* __restrict__ ofl_list, int E) {
  int i0 = blockIdx.x * 1024 + threadIdx.x;
  int r[4], c[4];
  float w[4];
  bool ok[4];
#pragma unroll
  for (int j = 0; j < 4; ++j) {
    int e = i0 + j * 256;
    ok[j] = e < E;
    if (ok[j]) {
      r[j] = ei[e];
      c[j] = ei[(size_t)E + e];
      w[j] = expf(ew[e]);
    }
  }
  int pos[4];
#pragma unroll
  for (int j = 0; j < 4; ++j)
    if (ok[j]) pos[j] = atomicAdd(&cnt[c[j]], 1);
#pragma unroll
  for (int j = 0; j < 4; ++j) {
    if (!ok[j]) continue;
    if (pos[j] < CAP) {
      pairs[(size_t)c[j] * CAP + pos[j]] = make_int2(r[j], __float_as_int(w[j]));
    } else {
      int o = atomicAdd(ofl_cnt, 1);
      if (o < OCAP) ofl_list[o] = i0 + j * 256;
    }
  }
}

// deg[node] = 1 + sum of expw over its bucket (one wave per node).
__global__ void k_degb(const int2* __restrict__ pairs, const int* __restrict__ cnt,
                       float* __restrict__ deg, int N) {
  int node = blockIdx.x * 4 + (threadIdx.x >> 6);
  if (node >= N) return;
  int lane = threadIdx.x & 63;
  int n = cnt[node];
  n = n > CAP ? CAP : n;
  float v = 0.0f;
  if (lane < n) v = __int_as_float(pairs[(size_t)node * CAP + lane].y);
#pragma unroll
  for (int off = 32; off > 0; off >>= 1) v += __shfl_xor(v, off, 64);
  if (lane == 0) deg[node] = v + 1.0f;
}

// overflow edges' contribution to deg (expected zero iterations)
__global__ void k_dego(const float* __restrict__ ew, const int* __restrict__ ei,
                       const int* __restrict__ ofl_cnt, const int* __restrict__ ofl_list,
                       float* __restrict__ deg, int E) {
  int tot = *ofl_cnt;
  if (tot > OCAP) tot = OCAP;
  for (int i = blockIdx.x * blockDim.x + threadIdx.x; i < tot;
       i += gridDim.x * blockDim.x) {
    int e = ofl_list[i];
    atomicAdd(&deg[ei[(size_t)E + e]], expf(ew[e]));
  }
}

__global__ void k_dinvf(float* __restrict__ deg, int N) {
  int i = blockIdx.x * blockDim.x + threadIdx.x;
  if (i < N) deg[i] = rsqrtf(deg[i]);
}

// out[orow,64](fp16) = transform(in)[gr,CIN] @ W[CIN,64]
// 64 rows/block, K-chunked (KC=64): ws 16KB + xs 17.4KB = 33.4KB LDS.
// Thread (rg,cg): rows rg*4..+3, cols cg*4..+3, acc[4][4].
// TR: input fp16 raw; v -> relu(v+bias)*sc+sh at staging (TR only when CIN=64).
// PERM: input rows [b][node] order, output row = node*2+b.
template<int CIN, bool TR, bool PERM>
__global__ void k_gemm(const void* __restrict__ in_, const float* __restrict__ W,
                       __half* __restrict__ out, int nrows, int N,
                       const float* __restrict__ bias, const float* __restrict__ scsh) {
  constexpr int RT = 64;           // rows per block
  constexpr int KC = 64;           // k per chunk
  constexpr int NCH = CIN / KC;    // chunks
  constexpr int S = KC + 4;        // xs row stride (floats)
  __shared__ float ws[KC * 64];    // 16 KB
  __shared__ float xs[RT * S];     // 17.4 KB

  int tid = threadIdx.x;
  int row0 = blockIdx.x * RT;
  int rg = tid >> 4;    // 0..15
  int cg = tid & 15;    // 0..15
  int c0 = cg * 4;
  int r0 = rg * 4;

  float acc[4][4];
#pragma unroll
  for (int i = 0; i < 4; ++i)
#pragma unroll
    for (int j = 0; j < 4; ++j) acc[i][j] = 0.0f;

  for (int ch = 0; ch < NCH; ++ch) {
    if (ch) __syncthreads();
    // stage W chunk: KC*16 float4, contiguous
    const float4* Wp = (const float4*)(W + (size_t)ch * KC * 64);
    for (int s = tid; s < KC * 16; s += 256)
      ((float4*)ws)[s] = Wp[s];
    // stage x chunk: RT rows x 16 float4 slots
    for (int s = tid; s < RT * 16; s += 256) {
      int r = s >> 4, k4 = s & 15;
      int gr = row0 + r;
      int kg = ch * KC + k4 * 4;   // global k
      float4 v = make_float4(0.f, 0.f, 0.f, 0.f);
      if (gr < nrows) {
        if (TR) {
          const __half* in = (const __half*)in_;
          uint2 u = *(const uint2*)(in + (size_t)gr * CIN + kg);
          float2 fa = __half22float2(u2h(u.x));
          float2 fb = __half22float2(u2h(u.y));
          v = make_float4(fa.x, fa.y, fb.x, fb.y);
        } else {
          const float* in = (const float*)in_;
          v = *(const float4*)(in + (size_t)gr * CIN + kg);
        }
      }
      if (TR) {
        float4 bb = *(const float4*)(bias + kg);
        float4 sc = *(const float4*)(scsh + kg);
        float4 sh = *(const float4*)(scsh + 64 + kg);
        v.x = fmaxf(v.x + bb.x, 0.f) * sc.x + sh.x;
        v.y = fmaxf(v.y + bb.y, 0.f) * sc.y + sh.y;
        v.z = fmaxf(v.z + bb.z, 0.f) * sc.z + sh.z;
        v.w = fmaxf(v.w + bb.w, 0.f) * sc.w + sh.w;
      }
      *(float4*)&xs[r * S + k4 * 4] = v;
    }
    __syncthreads();

#pragma unroll 2
    for (int kk = 0; kk < KC; kk += 4) {
      float4 wv0 = *(const float4*)&ws[(kk + 0) * 64 + c0];
      float4 wv1 = *(const float4*)&ws[(kk + 1) * 64 + c0];
      float4 wv2 = *(const float4*)&ws[(kk + 2) * 64 + c0];
      float4 wv3 = *(const float4*)&ws[(kk + 3) * 64 + c0];
#pragma unroll
      for (int i = 0; i < 4; ++i) {
        float4 xv = *(const float4*)&xs[(r0 + i) * S + kk];
        acc[i][0] = fmaf(xv.x, wv0.x, acc[i][0]);
        acc[i][1] = fmaf(xv.x, wv0.y, acc[i][1]);
        acc[i][2] = fmaf(xv.x, wv0.z, acc[i][2]);
        acc[i][3] = fmaf(xv.x, wv0.w, acc[i][3]);
        acc[i][0] = fmaf(xv.y, wv1.x, acc[i][0]);
        acc[i][1] = fmaf(xv.y, wv1.y, acc[i][1]);
        acc[i][2] = fmaf(xv.y, wv1.z, acc[i][2]);
        acc[i][3] = fmaf(xv.y, wv1.w, acc[i][3]);
        acc[i][0] = fmaf(xv.z, wv2.x, acc[i][0]);
        acc[i][1] = fmaf(xv.z, wv2.y, acc[i][1]);
        acc[i][2] = fmaf(xv.z, wv2.z, acc[i][2]);
        acc[i][3] = fmaf(xv.z, wv2.w, acc[i][3]);
        acc[i][0] = fmaf(xv.w, wv3.x, acc[i][0]);
        acc[i][1] = fmaf(xv.w, wv3.y, acc[i][1]);
        acc[i][2] = fmaf(xv.w, wv3.z, acc[i][2]);
        acc[i][3] = fmaf(xv.w, wv3.w, acc[i][3]);
      }
    }
  }

#pragma unroll
  for (int i = 0; i < 4; ++i) {
    int gr = row0 + r0 + i;
    if (gr < nrows) {
      int orow = PERM ? ((gr < N) ? gr * 2 : (gr - N) * 2 + 1) : gr;
      __half2 h01 = __floats2half2_rn(acc[i][0], acc[i][1]);
      __half2 h23 = __floats2half2_rn(acc[i][2], acc[i][3]);
      *(uint2*)(out + (size_t)orow * 64 + c0) = make_uint2(h2u(h01), h2u(h23));
    }
  }
}

// One wave per node; lane i holds half2 = channels (2i,2i+1) of the 128
// batch-fused channels. raw = dinv_c*(dinv_c*self + sum expw_k*dinv_rk*h_rk)
__global__ void k_agg(const __half* __restrict__ h, const int2* __restrict__ pairs,
                      const int* __restrict__ cnt, const float* __restrict__ dinv,
                      __half* __restrict__ raw, int N) {
  int node = blockIdx.x * 4 + (threadIdx.x >> 6);
  if (node >= N) return;
  int lane = threadIdx.x & 63;
  const __half2* hv = (const __half2*)h;    // 64 half2 per node-row (256 B)
  float dc = dinv[node];
  float2 self = __half22float2(hv[(size_t)node * 64 + lane]);
  float2 acc = make_float2(self.x * dc, self.y * dc);
  int n = cnt[node];
  n = n > CAP ? CAP : n;
  const int2* pp = pairs + (size_t)node * CAP;
  int k = 0;
  for (; k + 8 <= n; k += 8) {
    int2 p[8];
#pragma unroll
    for (int q = 0; q < 8; ++q) p[q] = pp[k + q];
    float dr[8];
#pragma unroll
    for (int q = 0; q < 8; ++q) dr[q] = dinv[p[q].x];
    __half2 v[8];
#pragma unroll
    for (int q = 0; q < 8; ++q) v[q] = hv[(size_t)p[q].x * 64 + lane];
#pragma unroll
    for (int q = 0; q < 8; ++q) {
      float w = __int_as_float(p[q].y) * dr[q];
      float2 f = __half22float2(v[q]);
      acc.x = fmaf(w, f.x, acc.x);
      acc.y = fmaf(w, f.y, acc.y);
    }
  }
  for (; k < n; ++k) {
    int2 p = pp[k];
    float w = __int_as_float(p.y) * dinv[p.x];
    float2 f = __half22float2(hv[(size_t)p.x * 64 + lane]);
    acc.x = fmaf(w, f.x, acc.x);
    acc.y = fmaf(w, f.y, acc.y);
  }
  ((__half2*)raw)[(size_t)node * 64 + lane] =
      __floats2half2_rn(acc.x * dc, acc.y * dc);
}

// Exact fallback for bucket overflow (expected empty). CAS on packed half2.
__global__ void k_ofl(const float* __restrict__ ew, const int* __restrict__ ei,
                      const float* __restrict__ dinv, const int* __restrict__ ofl_cnt,
                      const int* __restrict__ ofl_list,
                      const __half* __restrict__ h, __half* __restrict__ raw,
                      int N, int E) {
  int tot = *ofl_cnt;
  if (tot > OCAP) tot = OCAP;
  for (int i = blockIdx.x * blockDim.x + threadIdx.x; i < tot;
       i += gridDim.x * blockDim.x) {
    int e = ofl_list[i];
    int r = ei[e];
    int c = ei[(size_t)E + e];
    float nrm = dinv[r] * expf(ew[e]) * dinv[c];
    const __half2* hr = (const __half2*)(h + (size_t)r * 128);
    unsigned* dst = (unsigned*)(raw + (size_t)c * 128);
    for (int j = 0; j < 64; ++j) {
      float2 hv2 = __half22float2(hr[j]);
      unsigned old = dst[j], assumed;
      do {
        assumed = old;
        float2 cur = __half22float2(u2h(assumed));
        __half2 nv = __floats2half2_rn(cur.x + nrm * hv2.x, cur.y + nrm * hv2.y);
        old = atomicCAS(&dst[j], assumed, h2u(nv));
      } while (old != assumed);
    }
  }
}

// BN sums over y = relu(raw + bias): stats[c] += sum y, stats[64+c] += sum y^2
__global__ void k_stats(const __half* __restrict__ raw, const float* __restrict__ bias,
                        float* __restrict__ stats, int rows) {
  __shared__ float S[256], Q[256];
  int tid = threadIdx.x;
  int c = tid & 63, rg = tid >> 6;
  float s = 0.0f, q = 0.0f;
  for (int r = blockIdx.x * 4 + rg; r < rows; r += gridDim.x * 4) {
    float y = fmaxf(__half2float(raw[(size_t)r * 64 + c]) + bias[c], 0.0f);
    s += y;
    q += y * y;
  }
  S[tid] = s; Q[tid] = q;
  __syncthreads();
  if (tid < 64) {
    float ts = S[tid] + S[tid + 64] + S[tid + 128] + S[tid + 192];
    float tq = Q[tid] + Q[tid + 64] + Q[tid + 128] + Q[tid + 192];
    atomicAdd(&stats[tid], ts);
    atomicAdd(&stats[64 + tid], tq);
  }
}

__global__ void k_scale(const float* __restrict__ stats, const float* __restrict__ g,
                        const float* __restrict__ be, float* __restrict__ scsh,
                        float invCnt) {
  int c = threadIdx.x;
  if (c >= 64) return;
  float m = stats[c] * invCnt;
  float v = stats[64 + c] * invCnt - m * m;
  v = v < 0.0f ? 0.0f : v;
  float inv = rsqrtf(v + BN_EPS);
  float sc = g[c] * inv;
  scsh[c] = sc;
  scsh[64 + c] = be[c] - m * sc;
}

// rows are (node,b): r -> out[b*N + node]
__global__ void k_out(const __half* __restrict__ raw, const float* __restrict__ bias,
                      const float* __restrict__ scsh, const float* __restrict__ Wc,
                      const float* __restrict__ bc, float* __restrict__ out,
                      int rows, int N) {
  int row = blockIdx.x * 4 + (threadIdx.x >> 6);
  int c = threadIdx.x & 63;
  if (row >= rows) return;
  float v = fmaxf(__half2float(raw[(size_t)row * 64 + c]) + bias[c], 0.0f)
              * scsh[c] + scsh[64 + c];
  float p = v * Wc[c];
#pragma unroll
  for (int off = 32; off > 0; off >>= 1) p += __shfl_xor(p, off, 64);
  if (c == 0) {
    int node = row >> 1, b = row & 1;
    out[(size_t)b * N + node] = p + bc[0];
  }
}

extern "C" void kernel_launch(void* const* d_in, const int* in_sizes, int n_in,
                              void* d_out, int out_size, void* d_ws, size_t ws_size,
                              hipStream_t stream) {
  const float* x   = (const float*)d_in[0];
  const float* ew  = (const float*)d_in[1];
  const float* W1  = (const float*)d_in[2];
  const float* b1  = (const float*)d_in[3];
  const float* W2  = (const float*)d_in[4];
  const float* b2  = (const float*)d_in[5];
  const float* g1  = (const float*)d_in[6];
  const float* be1 = (const float*)d_in[7];
  const float* g2  = (const float*)d_in[8];
  const float* be2 = (const float*)d_in[9];
  const float* Wc  = (const float*)d_in[10];
  const float* bc  = (const float*)d_in[11];
  const int*   ei  = (const int*)d_in[12];

  const int E  = in_sizes[1];
  const int BN = in_sizes[0] / 128;  // B*N = 100000
  const int N  = BN / 2;

  char* w = (char*)d_ws;
  size_t off = 0;
  float* dinv   = (float*)(w + off); off += (size_t)N * 4;  // deg then dinv
  int*   cnt    = (int*)  (w + off); off += (size_t)N * 4;
  float* stats1 = (float*)(w + off); off += 512;
  float* stats2 = (float*)(w + off); off += 512;
  int*   oflc   = (int*)  (w + off); off += 16;
  size_t zbytes = off;               // everything above must start at 0
  float* scsh1  = (float*)(w + off); off += 512;
  float* scsh2  = (float*)(w + off); off += 512;
  int*   ofll   = (int*)  (w + off); off += (size_t)OCAP * 4;
  off = (off + 255) & ~(size_t)255;
  int2*   pairs = (int2*)  (w + off); off += (size_t)N * CAP * 8;
  __half* bufA  = (__half*)(w + off); off += (size_t)BN * 64 * 2;
  __half* bufB  = (__half*)(w + off); off += (size_t)BN * 64 * 2;

  float* out = (float*)d_out;

  hipMemsetAsync(w, 0, zbytes, stream);

  dim3 blk(256);
  int gE4 = (E + 1023) / 1024;
  int gN  = (N + 255) / 256;
  int gG  = (BN + 63) / 64;     // gemm: 64 rows/block
  int gR  = (BN + 3) / 4;
  int gA  = (N + 3) / 4;        // 1 wave per node (both batches fused)

  k_fill<<<gE4, blk, 0, stream>>>(ew, ei, cnt, pairs, oflc, ofll, E);
  k_degb<<<gA, blk, 0, stream>>>(pairs, cnt, dinv, N);
  k_dego<<<16, blk, 0, stream>>>(ew, ei, oflc, ofll, dinv, E);
  k_dinvf<<<gN, blk, 0, stream>>>(dinv, N);

  // ---- layer 1 ----  bufA = x @ W1  (rows -> node*2+b order)
  k_gemm<128, false, true><<<gG, blk, 0, stream>>>(x, W1, bufA, BN, N, nullptr, nullptr);
  k_agg<<<gA, blk, 0, stream>>>(bufA, pairs, cnt, dinv, bufB, N);
  k_ofl<<<16, blk, 0, stream>>>(ew, ei, dinv, oflc, ofll, bufA, bufB, N, E);
  k_stats<<<400, blk, 0, stream>>>(bufB, b1, stats1, BN);
  k_scale<<<1, 64, 0, stream>>>(stats1, g1, be1, scsh1, 1.0f / (float)BN);

  // ---- layer 2 ----  bufA = bn1(relu(bufB+b1)) @ W2  (row order preserved)
  k_gemm<64, true, false><<<gG, blk, 0, stream>>>(bufB, W2, bufA, BN, N, b1, scsh1);
  k_agg<<<gA, blk, 0, stream>>>(bufA, pairs, cnt, dinv, bufB, N);
  k_ofl<<<16, blk, 0, stream>>>(ew, ei, dinv, oflc, ofll, bufA, bufB, N, E);
  k_stats<<<400, blk, 0, stream>>>(bufB, b2, stats2, BN);
  k_scale<<<1, 64, 0, stream>>>(stats2, g2, be2, scsh2, 1.0f / (float)BN);

  // ---- head ----
  k_out<<<gR, blk, 0, stream>>>(bufB, b2, scsh2, Wc, bc, out, BN, N);
}